// Round 12
// baseline (515.020 us; speedup 1.0000x reference)
//
#include <hip/hip_runtime.h>
#include <math.h>

// Problem constants (from reference): B=16, Q=3000, C=1203
#define NB 16
#define NQR 3000
#define NC 1203

typedef float f32x4 __attribute__((ext_vector_type(4)));

// ---------------------------------------------------------------------------
// Decision math — FROZEN from round 3 (passed, absmax = 1 bf16 ulp).
// Fast path: hw exp + rcp, +/-1e-5 band; band elements redo the reference's
// exact f32 op-chain: f32(exp_f64(-x)), IEEE f32 add, IEEE f32 div.
// ---------------------------------------------------------------------------
__device__ __forceinline__ int lane_proc(float x, float t,
                                         float* __restrict__ s,
                                         float* __restrict__ k) {
    float pf = __builtin_amdgcn_rcpf(1.0f + __expf(-x));
    bool kp;
    float sc;
    if (pf > t + 1e-5f) {
        kp = true;  sc = pf;
    } else if (pf < t - 1e-5f) {
        kp = false; sc = 0.0f;
    } else {
        float e32 = (float)exp(-(double)x);   // correctly-rounded f32 exp
        float p32 = 1.0f / (1.0f + e32);      // IEEE f32 add + div
        kp = (p32 >= t);
        sc = kp ? p32 : 0.0f;
    }
    *s = sc;
    *k = kp ? 1.0f : 0.0f;
    return kp ? 1 : 0;
}

// ---------------------------------------------------------------------------
// Tiny zero-fill for boxes_out (48000 * 4 floats). Avoids hipMemsetAsync
// inside graph capture; boxes are then written via benign same-value races.
// ---------------------------------------------------------------------------
__global__ void k_zero(float* __restrict__ p, int n) {
    int i = blockIdx.x * 256 + threadIdx.x;
    if (i < n) p[i] = 0.0f;
}

// ---------------------------------------------------------------------------
// FUSED kernel: one workgroup = (batch b, 16-column tile). 256 threads =
// 16 cols (ci) x 16 q-lanes (qi); thread handles q = qi + 16k.
//
// Phase A: column max over all 3000 q (exact fmaxf chain, order-free),
//          LDS reduce across the 16 q-lanes, then the FROZEN f32 threshold
//          chain inline (f32(exp_f64(-m)), f32 add, f32 div, *0.5f;
//          absent class -> +INF).
// Phase B: re-read the same slab (L2/L3-hot: each wg re-reads its own
//          ~192 KB moments later), lane_proc, NT stores for scores/keep.
//          Per-row any-keep via ballot 16-lane group mask; group leader
//          writes boxes_out[row] = boxes[row] (same-value race across the
//          76 tiles; boxes_out pre-zeroed).
//
// This removes the serial pass1->k_main prefix (~42 us) and the inter-kernel
// MALL residency dependency that capped the re-read at ~50% hits.
// Tile index is XCD-chunk swizzled (bijective, 76 = 4*10 + 4*9) so adjacent
// tiles (which share cache lines at their 64 B-misaligned boundaries) land
// on the same XCD's L2.
// ---------------------------------------------------------------------------
__global__ __launch_bounds__(256) void k_fused(const float* __restrict__ logits,
                                               const float* __restrict__ boxes,
                                               const int* __restrict__ cls_present,
                                               float* __restrict__ scores,
                                               float* __restrict__ keep,
                                               float* __restrict__ boxes_out) {
    int tid = threadIdx.x;
    int ci  = tid & 15;
    int qi  = tid >> 4;                 // 0..15
    int b   = blockIdx.y;

    // XCD-chunk swizzle over 76 tiles, 8 XCDs: q=9, r=4 (bijective, m204 form)
    int ct0 = blockIdx.x;
    int xcd = ct0 & 7, idx = ct0 >> 3;
    int ct  = (xcd < 4) ? xcd * 10 + idx : 40 + (xcd - 4) * 9 + idx;

    int c   = ct * 16 + ci;
    bool cv = (c < NC);                 // last tile covers cols 1200..1202

    const float* lcol = logits + (size_t)b * NQR * NC + c;

    // ---- Phase A: column max over q = qi + 16k ----
    float m = -INFINITY;
    if (cv) {
        const float* p = lcol + (size_t)qi * NC;
        int k = 0;
        for (; k + 4 <= 184; k += 4) {      // k 0..183: q <= 15+16*183+48 < 3000
            float a0 = p[0];
            float a1 = p[16 * NC];
            float a2 = p[32 * NC];
            float a3 = p[48 * NC];
            m = fmaxf(m, fmaxf(fmaxf(a0, a1), fmaxf(a2, a3)));
            p += 64 * NC;
        }
        for (; k < 188; ++k) {              // k 184..187 with q-guard
            int q = qi + 16 * k;
            if (q < NQR) m = fmaxf(m, *p);
            p += 16 * NC;
        }
    }

    __shared__ float red[256];
    __shared__ float thrs[16];
    red[tid] = m;
    __syncthreads();
    if (tid < 16) {
        float mm = red[tid];
#pragma unroll
        for (int j = 1; j < 16; ++j)
            mm = fmaxf(mm, red[j * 16 + tid]);
        int cc = ct * 16 + tid;
        float t = INFINITY;
        if (cc < NC && cls_present[b * NC + cc]) {
            float e32  = (float)exp(-(double)mm);   // frozen f32-chain numerics
            float ptop = 1.0f / (1.0f + e32);
            t = 0.5f * ptop;
        }
        thrs[tid] = t;
    }
    __syncthreads();
    float thr = thrs[ci];

    // ---- Phase B: elementwise outputs + per-row boxes ----
    const float* lp = lcol + (size_t)qi * NC;
    float* sp = scores + (size_t)b * NQR * NC + c + (size_t)qi * NC;
    float* kp = keep   + (size_t)b * NQR * NC + c + (size_t)qi * NC;
    int gsh = (qi & 3) * 16;            // this row-group's 16-bit ballot field

#pragma unroll 2
    for (int k = 0; k < 188; ++k) {
        int q = qi + 16 * k;
        int anyk = 0;
        bool act = cv && (q < NQR);
        if (act) {
            float sv, kv;
            anyk = lane_proc(*lp, thr, &sv, &kv);
            __builtin_nontemporal_store(sv, sp);
            __builtin_nontemporal_store(kv, kp);
        }
        unsigned long long bal = __ballot(anyk);
        unsigned rowm = (unsigned)(bal >> gsh) & 0xFFFFu;
        if (ci == 0 && q < NQR && rowm) {
            size_t row = (size_t)b * NQR + q;
            f32x4 bx = *(const f32x4*)(boxes + row * 4);
            *(f32x4*)(boxes_out + row * 4) = bx;    // same-value race: benign
        }
        lp += 16 * NC;
        sp += 16 * NC;
        kp += 16 * NC;
    }
}

extern "C" void kernel_launch(void* const* d_in, const int* in_sizes, int n_in,
                              void* d_out, int out_size, void* d_ws, size_t ws_size,
                              hipStream_t stream) {
    const float* logits      = (const float*)d_in[0];  // [B,Q,C] f32
    const float* boxes       = (const float*)d_in[1];  // [B,Q,4] f32
    // d_in[2] = target_sizes (unused by reference math)
    const int*   cls_present = (const int*)d_in[3];    // [B,C] 0/1

    float* scores    = (float*)d_out;                       // [B,Q,C]
    float* keep      = scores + (size_t)NB * NQR * NC;      // [B,Q,C]
    float* boxes_out = keep + (size_t)NB * NQR * NC;        // [B,Q,4]

    // boxes_out must start at zero every call (harness poisons d_out).
    int nbx = NB * NQR * 4;                                 // 192000 floats
    k_zero<<<(nbx + 255) / 256, 256, 0, stream>>>(boxes_out, nbx);

    dim3 g(76, NB);                                         // 76 col-tiles x 16 b
    k_fused<<<g, 256, 0, stream>>>(logits, boxes, cls_present,
                                   scores, keep, boxes_out);
}

// Round 13
// 327.316 us; speedup vs baseline: 1.5735x; 1.5735x over previous
//
#include <hip/hip_runtime.h>
#include <math.h>

// Problem constants (from reference): B=16, Q=3000, C=1203
#define NB 16
#define NQR 3000
#define NC 1203

// DIAGNOSTIC ROUND: k_main body executed REP times inside one dispatch so the
// dispatch exceeds the harness fill kernels' ~270 us and appears in the
// rocprof top-5 with its own FETCH/WRITE/occupancy counters. Idempotent:
// identical values stored each rep. Revert to 1 next round.
#define REP 2

typedef float f32x4 __attribute__((ext_vector_type(4)));

// ---------------------------------------------------------------------------
// Decision math — FROZEN from round 3 (passed, absmax = 1 bf16 ulp).
// ---------------------------------------------------------------------------
__device__ __forceinline__ int lane_proc(float x, float t,
                                         float* __restrict__ s,
                                         float* __restrict__ k) {
    float pf = __builtin_amdgcn_rcpf(1.0f + __expf(-x));
    bool kp;
    float sc;
    if (pf > t + 1e-5f) {
        kp = true;  sc = pf;
    } else if (pf < t - 1e-5f) {
        kp = false; sc = 0.0f;
    } else {
        float e32 = (float)exp(-(double)x);   // correctly-rounded f32 exp
        float p32 = 1.0f / (1.0f + e32);      // IEEE f32 add + div
        kp = (p32 >= t);
        sc = kp ? p32 : 0.0f;
    }
    *s = sc;
    *k = kp ? 1.0f : 0.0f;
    return kp ? 1 : 0;
}

// ---------------------------------------------------------------------------
// Kernel 1: partial max of logits over a Q-chunk, per (b,c). [R9-exact]
// ---------------------------------------------------------------------------
__global__ void k_partial_max(const float* __restrict__ logits,
                              float* __restrict__ partial,
                              int qc) {
    int c = blockIdx.x * blockDim.x + threadIdx.x;
    int b = blockIdx.y;
    int z = blockIdx.z;
    if (c >= NC) return;
    int q0 = z * qc;
    int q1 = min(NQR, q0 + qc);
    float m = -INFINITY;
    const float* p = logits + ((size_t)(b * NQR + q0)) * NC + c;
    int q = q0;
    for (; q + 8 <= q1; q += 8) {
        float a0 = p[0];
        float a1 = p[NC];
        float a2 = p[2 * NC];
        float a3 = p[3 * NC];
        float a4 = p[4 * NC];
        float a5 = p[5 * NC];
        float a6 = p[6 * NC];
        float a7 = p[7 * NC];
        float m01 = fmaxf(a0, a1), m23 = fmaxf(a2, a3);
        float m45 = fmaxf(a4, a5), m67 = fmaxf(a6, a7);
        m = fmaxf(m, fmaxf(fmaxf(m01, m23), fmaxf(m45, m67)));
        p += 8 * NC;
    }
    for (; q < q1; ++q) {
        m = fmaxf(m, *p);
        p += NC;
    }
    partial[((size_t)z * NB + b) * NC + c] = m;
}

// ---------------------------------------------------------------------------
// Kernel 2: combine partial maxes -> f32-chain threshold (frozen numerics).
// ---------------------------------------------------------------------------
__global__ void k_thresh(const float* __restrict__ partial,
                         const int* __restrict__ cls_present,
                         float* __restrict__ thrf,
                         int nz) {
    int c = blockIdx.x * blockDim.x + threadIdx.x;
    int b = blockIdx.y;
    if (c >= NC) return;
    float m = -INFINITY;
    for (int z = 0; z < nz; ++z)
        m = fmaxf(m, partial[((size_t)z * NB + b) * NC + c]);
    float t;
    if (cls_present[b * NC + c]) {
        float e32  = (float)exp(-(double)m);
        float ptop = 1.0f / (1.0f + e32);
        t = 0.5f * ptop;
    } else {
        t = INFINITY;
    }
    thrf[(size_t)b * NC + c] = t;
}

// ---------------------------------------------------------------------------
// Kernel 3: R9-exact wave-per-row pass, body repeated REP times (diagnostic).
// ---------------------------------------------------------------------------
__global__ __launch_bounds__(256) void k_main(const float* __restrict__ logits,
                                              const float* __restrict__ boxes,
                                              const float* __restrict__ thrf,
                                              float* __restrict__ scores,
                                              float* __restrict__ keep,
                                              float* __restrict__ boxes_out) {
    int wid  = threadIdx.x >> 6;
    int lane = threadIdx.x & 63;
    int row  = blockIdx.x * 4 + wid;          // grid sized exactly: 48000 rows
    int b    = row / NQR;                     // same for all 4 waves in block

    __shared__ float tsh[NC];
    {
        const float* tf = thrf + (size_t)b * NC;
        for (int i = threadIdx.x; i < NC; i += 256)
            tsh[i] = tf[i];
    }
    __syncthreads();

    const float* lrow = logits + (size_t)row * NC;
    float* srow = scores + (size_t)row * NC;
    float* krow = keep + (size_t)row * NC;

    int head = row & 3;

    for (int rep = 0; rep < REP; ++rep) {
        int any = 0;
        float sv, kv;

        // head scalars (0..head-1)
        if (lane < head) {
            int c = lane;
            any |= lane_proc(lrow[c], tsh[c], &sv, &kv);
            __builtin_nontemporal_store(sv, srow + c);
            __builtin_nontemporal_store(kv, krow + c);
        }

        // aligned f32x4 body: 300 vectors (simple loop, NT stores)
        for (int v = lane; v < 300; v += 64) {
            int c = head + 4 * v;
            f32x4 x4 = *(const f32x4*)(lrow + c);
            f32x4 s4, k4;
            float s0, s1, s2, s3, k0, k1, k2, k3;
            any |= lane_proc(x4.x, tsh[c + 0], &s0, &k0);
            any |= lane_proc(x4.y, tsh[c + 1], &s1, &k1);
            any |= lane_proc(x4.z, tsh[c + 2], &s2, &k2);
            any |= lane_proc(x4.w, tsh[c + 3], &s3, &k3);
            s4 = (f32x4){s0, s1, s2, s3};
            k4 = (f32x4){k0, k1, k2, k3};
            __builtin_nontemporal_store(s4, (f32x4*)(srow + c));
            __builtin_nontemporal_store(k4, (f32x4*)(krow + c));
        }

        // tail scalars (count = 3 - head)
        if (lane < 3 - head) {
            int c = head + 1200 + lane;
            any |= lane_proc(lrow[c], tsh[c], &sv, &kv);
            __builtin_nontemporal_store(sv, srow + c);
            __builtin_nontemporal_store(kv, krow + c);
        }

        unsigned long long m = __ballot(any);
        if (lane == 0) {
            float mm = m ? 1.0f : 0.0f;
            f32x4 bx = *(const f32x4*)(boxes + (size_t)row * 4);
            f32x4 o = bx * mm;
            *(f32x4*)(boxes_out + (size_t)row * 4) = o;
        }
    }
}

extern "C" void kernel_launch(void* const* d_in, const int* in_sizes, int n_in,
                              void* d_out, int out_size, void* d_ws, size_t ws_size,
                              hipStream_t stream) {
    const float* logits      = (const float*)d_in[0];  // [B,Q,C] f32
    const float* boxes       = (const float*)d_in[1];  // [B,Q,4] f32
    // d_in[2] = target_sizes (unused by reference math)
    const int*   cls_present = (const int*)d_in[3];    // [B,C] 0/1

    float* scores    = (float*)d_out;                       // [B,Q,C]
    float* keep      = scores + (size_t)NB * NQR * NC;      // [B,Q,C]
    float* boxes_out = keep + (size_t)NB * NQR * NC;        // [B,Q,4]

    // Workspace layout: partial[nz][B][C] f32 | thrf[B][C] f32
    int nz = 25;
    while (nz > 1 && ((size_t)nz + 1) * NB * NC * sizeof(float) > ws_size)
        nz /= 2;
    float* partial = (float*)d_ws;
    float* thrf    = partial + (size_t)nz * NB * NC;
    int qc = (NQR + nz - 1) / nz;

    dim3 gmax((NC + 255) / 256, NB, nz);
    k_partial_max<<<gmax, 256, 0, stream>>>(logits, partial, qc);

    dim3 gthr((NC + 255) / 256, NB);
    k_thresh<<<gthr, 256, 0, stream>>>(partial, cls_present, thrf, nz);

    k_main<<<(NB * NQR) / 4, 256, 0, stream>>>(logits, boxes, thrf,
                                               scores, keep, boxes_out);
}